// Round 11
// baseline (54.526 us; speedup 1.0000x reference)
//
#include <hip/hip_runtime.h>

typedef __attribute__((ext_vector_type(8))) short bf16x8;
typedef __attribute__((ext_vector_type(4))) float f32x4;

#define ROWS 588             // 196 patches * 3 channels
#define WROWS 640            // W rows per b, padded to chunk multiple
#define NCHUNK 10            // 640/64 row-chunks per batch
#define SSTRIDE 5376         // 128*3*14 floats
#define WB_BYTES 163840      // WROWS*256

// pack two f32 -> two bf16 (RNE) in one u32
static __device__ __forceinline__ unsigned f2bf2(float a, float b) {
    union { float f; unsigned u; } x, y; x.f = a; y.f = b;
    unsigned lo = (x.u + 0x7FFFu + ((x.u >> 16) & 1u)) >> 16;
    unsigned hi = (y.u + 0x7FFFu + ((y.u >> 16) & 1u)) & 0xFFFF0000u;
    return lo | hi;
}

// ---- Kernel 1: prep — BM k-half + W row-half (softmax, PRE-SWIZZLED) --------
// block (b, zb): BM k-half zb  AND  W rows [zb*294, zb*294+294) (+zero pad)
__global__ __launch_bounds__(512) void prep(
    const float* __restrict__ h_scores, // [B,128,3,14]
    const float* __restrict__ v_score,  // [B,128,3,14]
    const float* __restrict__ h_base,   // [B,128,16]
    const float* __restrict__ v_base,   // [B,128,16]
    uint4* __restrict__ bmv,            // [B,16,256] uint4: [k>>3][mn][8k] bf16
    char* __restrict__ w_ws)            // [B,640,256B] bf16 rows, XOR-swizzled
{
    __shared__ float hbT[16][68], vbT[16][68];   // [m][k'] pad 68
    __shared__ float sh[SSTRIDE], sv[SSTRIDE];   // full scores, [k][42] layout
    const int b = blockIdx.x, zb = blockIdx.y, t = threadIdx.x;

    // stage bases for this k-half (1024 floats each; [k'][m] -> transposed)
    const float* hg = h_base + (size_t)b * 2048 + zb * 1024;
    const float* vg = v_base + (size_t)b * 2048 + zb * 1024;
#pragma unroll
    for (int i = 0; i < 2; ++i) {
        const int idx = t + i * 512;            // k' = idx>>4, m = idx&15
        hbT[idx & 15][idx >> 4] = hg[idx];
        vbT[idx & 15][idx >> 4] = vg[idx];
    }
    // stage full score tensors (coalesced linear copy)
    const float* hsb = h_scores + (size_t)b * SSTRIDE;
    const float* vsb = v_score  + (size_t)b * SSTRIDE;
    for (int e = t; e < SSTRIDE; e += 512) { sh[e] = hsb[e]; sv[e] = vsb[e]; }
    __syncthreads();

    // ---- BM half: thread (mn = t&255, kq2 = t>>8), 4 kc8-chunks each ----
    {
        const int mn = t & 255, kq2 = t >> 8;
        const int m = mn >> 4, n = mn & 15;
        uint4* dst = bmv + ((size_t)b * 16 + zb * 8 + kq2 * 4) * 256 + mn;
#pragma unroll
        for (int i = 0; i < 4; ++i) {
            const int kp = (kq2 * 4 + i) * 8;   // local k' base
            float p[8];
#pragma unroll
            for (int j = 0; j < 8; ++j) p[j] = vbT[m][kp + j] * hbT[n][kp + j];
            uint4 u = { f2bf2(p[0],p[1]), f2bf2(p[2],p[3]),
                        f2bf2(p[4],p[5]), f2bf2(p[6],p[7]) };
            dst[i * 256] = u;
        }
    }

    // ---- W rows: thread pair = (row r2 = t>>1, k-half kh = t&1) ----
    char* wb = w_ws + (size_t)b * WB_BYTES;
    const int r2 = t >> 1, kh = t & 1;
    const int lim = zb ? 346 : 294;             // zb=1 covers 294 real + 52 pad
#pragma unroll
    for (int rr = 0; rr < 2; ++rr) {
        const int local = rr * 256 + r2;
        if (local < lim) {
            const int grow = zb * 294 + local;
            const int sw = (grow & 7) << 4;
            char* wrow = wb + grow * 256;
            if (grow < ROWS) {
                const int p = grow / 3, c = grow - p * 3;
                const int np = p / 14, mp = p - np * 14;
                const int hix = c * 14 + np, vix = c * 14 + mp;
                float sc[64];
#pragma unroll
                for (int j = 0; j < 64; ++j) {
                    const int k = kh * 64 + j;
                    sc[j] = sh[k * 42 + hix] * sv[k * 42 + vix];
                }
                float mx = sc[0];
#pragma unroll
                for (int j = 1; j < 64; ++j) mx = fmaxf(mx, sc[j]);
                mx = fmaxf(mx, __shfl_xor(mx, 1));       // partner = other k-half
                float sum = 0.f;
#pragma unroll
                for (int j = 0; j < 64; ++j) { sc[j] = __expf(sc[j] - mx); sum += sc[j]; }
                sum += __shfl_xor(sum, 1);
                const float inv = 1.f / sum;
#pragma unroll
                for (int s = 0; s < 8; ++s) {
                    uint4 u = { f2bf2(sc[s*8+0]*inv, sc[s*8+1]*inv),
                                f2bf2(sc[s*8+2]*inv, sc[s*8+3]*inv),
                                f2bf2(sc[s*8+4]*inv, sc[s*8+5]*inv),
                                f2bf2(sc[s*8+6]*inv, sc[s*8+7]*inv) };
                    *(uint4*)(wrow + ((kh * 128 + s * 16) ^ sw)) = u;
                }
            } else {                            // pad rows 588..639 -> zeros
                uint4 z = {0u, 0u, 0u, 0u};
#pragma unroll
                for (int s = 0; s < 8; ++s)
                    *(uint4*)(wrow + ((kh * 128 + s * 16) ^ sw)) = z;
            }
        }
    }
}

// ---- Kernel 2: W via global_load_lds + MFMA GEMM (no softmax here) ----------
__global__ __launch_bounds__(256) void patch_gemm(
    const char* __restrict__ w_ws,      // [B,640,256B] pre-swizzled bf16 rows
    const uint4* __restrict__ bmv,
    float* __restrict__ out)            // [B,588,256]
{
    __shared__ __align__(16) char lds[16384];   // W: 64 rows x 256B (swizzle in data)

    const int bid = blockIdx.x;
    const int xcd = bid & 7, rest = bid >> 3;   // bijective: b%8 == XCD == prep writer
    const int b = (rest / NCHUNK) * 8 + xcd;
    const int chunk = rest % NCHUNK;
    const int t = threadIdx.x;
    const int w = t >> 6, lane = t & 63;

    // ---- async W-chunk stage: 16KB, 4 x dwordx4 per wave, zero VGPR ----
    {
        const char* src = w_ws + (size_t)b * WB_BYTES + chunk * 16384;
#pragma unroll
        for (int i = 0; i < 4; ++i) {
            const int off = i * 4096 + w * 1024;
            __builtin_amdgcn_global_load_lds(
                (const __attribute__((address_space(1))) void*)(src + off + lane * 16),
                (__attribute__((address_space(3))) void*)(lds + off), 16, 0, 0);
        }
    }
    __syncthreads();    // barrier drains vmcnt -> W resident

    // ---- MFMA: wave w owns rows [wrh*32,+32) and mn-half wnh*128 ----
    const int wrh = w >> 1, wnh = w & 1;
    const int lr = lane & 15, lg = lane >> 4;

    bf16x8 wfrag[2][4];
#pragma unroll
    for (int mi = 0; mi < 2; ++mi) {
        const int r2 = wrh * 32 + mi * 16 + lr;
        const int sw = (r2 & 7) << 4;
#pragma unroll
        for (int kc = 0; kc < 4; ++kc)
            wfrag[mi][kc] = *(const bf16x8*)(lds + r2 * 256 + ((kc * 64 + lg * 16) ^ sw));
    }

    const uint4* bmb = bmv + (size_t)b * 4096;

    f32x4 acc[2][8];
#pragma unroll
    for (int mi = 0; mi < 2; ++mi)
#pragma unroll
        for (int nt = 0; nt < 8; ++nt)
            acc[mi][nt] = (f32x4){0.f, 0.f, 0.f, 0.f};

    // D = BM x W^T (operand-swapped): D rows = mn, D cols = out rows (verified R3)
#pragma unroll
    for (int nt = 0; nt < 8; ++nt) {
        const int mn = wnh * 128 + nt * 16 + lr;
#pragma unroll
        for (int kc = 0; kc < 4; ++kc) {
            uint4 raw = bmb[(kc * 4 + lg) * 256 + mn];   // 256B-coalesced, L2-hot
            bf16x8 bfrag = *(bf16x8*)&raw;
            acc[0][nt] = __builtin_amdgcn_mfma_f32_16x16x32_bf16(bfrag, wfrag[0][kc], acc[0][nt], 0, 0, 0);
            acc[1][nt] = __builtin_amdgcn_mfma_f32_16x16x32_bf16(bfrag, wfrag[1][kc], acc[1][nt], 0, 0, 0);
        }
    }

    // ---- store: lane holds D[mn = nt*16+lg*4+reg][outrow = tile+lr] ----
    float* ob = out + (size_t)b * (ROWS * 256);
#pragma unroll
    for (int mi = 0; mi < 2; ++mi) {
        const int gr = chunk * 64 + wrh * 32 + mi * 16 + lr;
        if (gr < ROWS) {
            float* orow = ob + (size_t)gr * 256 + wnh * 128 + lg * 4;
#pragma unroll
            for (int nt = 0; nt < 8; ++nt)
                __builtin_nontemporal_store(acc[mi][nt], (f32x4*)(orow + nt * 16));
        }
    }
}

extern "C" void kernel_launch(void* const* d_in, const int* in_sizes, int n_in,
                              void* d_out, int out_size, void* d_ws, size_t ws_size,
                              hipStream_t stream) {
    const float* h_scores = (const float*)d_in[0];
    const float* v_score  = (const float*)d_in[1];
    const float* h_base   = (const float*)d_in[2];
    const float* v_base   = (const float*)d_in[3];
    float* out = (float*)d_out;

    const int B = in_sizes[0] / SSTRIDE;          // 128

    // ws: [0,8MB) bmv | [8MB, 8MB+20MB) W (pre-swizzled bf16 rows)
    uint4* bmv = (uint4*)d_ws;
    char* w_ws = (char*)d_ws + (size_t)8 * 1024 * 1024;

    prep<<<dim3(B, 2), 512, 0, stream>>>(h_scores, v_score, h_base, v_base, bmv, w_ws);
    patch_gemm<<<B * NCHUNK, 256, 0, stream>>>(w_ws, bmv, out);
}